// Round 10
// baseline (652.806 us; speedup 1.0000x reference)
//
#include <hip/hip_runtime.h>
#include <stdint.h>

#define N_NODES 50000
#define N_EDGES 600000
#define DIM 128
#define N_TILES (N_EDGES / 64)   // 9375
#define NODE_BLOCKS 782          // ceil(50000/64)
#define CE_BLOCKS 1875           // 9375 / 5 tiles each, exact
#define BUCKET_BLOCKS 2344       // ceil(600000/256)
#define GATHER_BLOCKS 2048       // 8192 waves, node-aligned ranges
#define APPLY_BLOCKS 2048        // 8192 waves, exactly resident

typedef __attribute__((ext_vector_type(8))) short bf16x8;
typedef __attribute__((ext_vector_type(4))) float f32x4;
typedef __attribute__((ext_vector_type(2))) float f32x2;
typedef __attribute__((ext_vector_type(4))) unsigned int u32x4;
typedef __attribute__((ext_vector_type(2))) unsigned int u32x2;

__device__ inline unsigned short f2bf(float f) {
  unsigned u = __builtin_bit_cast(unsigned, f);
  unsigned r = 0x7fffu + ((u >> 16) & 1u);
  return (unsigned short)((u + r) >> 16);
}
__device__ inline float bf2f_lo(unsigned p) { return __builtin_bit_cast(float, p << 16); }
__device__ inline float bf2f_hi(unsigned p) { return __builtin_bit_cast(float, p & 0xffff0000u); }

// ---- LDS staging (swizzled bf16 tiles, row stride 256 B) ----
__device__ inline void stage_pack_store(char* lds, int row, int f, f32x4 v0, f32x4 v1) {
  u32x4 q;
  q[0] = (unsigned)f2bf(v0[0]) | ((unsigned)f2bf(v0[1]) << 16);
  q[1] = (unsigned)f2bf(v0[2]) | ((unsigned)f2bf(v0[3]) << 16);
  q[2] = (unsigned)f2bf(v1[0]) | ((unsigned)f2bf(v1[1]) << 16);
  q[3] = (unsigned)f2bf(v1[2]) | ((unsigned)f2bf(v1[3]) << 16);
  int byte = (f * 16) ^ ((row & 7) << 4);
  *(u32x4*)(lds + row * 256 + byte) = q;
}

__device__ inline void stage_tile_f32(const float* __restrict__ src, int row0,
                                      int nvalid, char* lds) {
#pragma unroll
  for (int it = 0; it < 4; ++it) {
    int c = it * 256 + threadIdx.x;
    int row = c >> 4, f = c & 15;
    f32x4 v0 = {0, 0, 0, 0}, v1 = {0, 0, 0, 0};
    if (row < nvalid) {
      const f32x4* p = (const f32x4*)(src + (size_t)(row0 + row) * DIM + f * 8);
      v0 = p[0]; v1 = p[1];
    }
    stage_pack_store(lds, row, f, v0, v1);
  }
}

__device__ inline void stage_w(const unsigned short* __restrict__ wbf, char* lds) {
#pragma unroll
  for (int it = 0; it < 8; ++it) {
    int c = it * 256 + threadIdx.x;
    int row = c >> 4, f = c & 15;
    u32x4 q = *(const u32x4*)(wbf + row * 128 + f * 8);
    int byte = (f * 16) ^ ((row & 7) << 4);
    *(u32x4*)(lds + row * 256 + byte) = q;
  }
}

__device__ inline bf16x8 read_frag(const char* lds, int row, int ks, int lane) {
  int byte = ks * 64 + ((lane >> 4) * 16);
  byte ^= ((row & 7) << 4);
  return *(const bf16x8*)(lds + row * 256 + byte);
}

// ---- K0: weight conversion + dst histogram ----
__global__ void setup_kernel(const float* __restrict__ a, const float* __restrict__ b,
                             const float* __restrict__ c, const float* __restrict__ d,
                             const float* __restrict__ e5, unsigned short* __restrict__ out,
                             const int* __restrict__ dst, int* __restrict__ counts) {
  int i = blockIdx.x * 256 + threadIdx.x;
  if (i < 5 * 16384) {
    int m = i >> 14, k = i & 16383;
    const float* p = (m == 0) ? a : (m == 1) ? b : (m == 2) ? c : (m == 3) ? d : e5;
    out[i] = f2bf(p[k]);
  }
  if (i < N_EDGES) atomicAdd(&counts[dst[i]], 1);
}

__global__ __launch_bounds__(1024) void scan_kernel(const int* __restrict__ counts,
                                                    int* __restrict__ offsets) {
  __shared__ int part[1024];
  const int CHK = 49;
  int t = threadIdx.x;
  int base = t * CHK;
  int s = 0;
  for (int k = 0; k < CHK; ++k) {
    int i = base + k;
    if (i < N_NODES) s += counts[i];
  }
  part[t] = s;
  __syncthreads();
  for (int off = 1; off < 1024; off <<= 1) {
    int v = part[t];
    int u = (t >= off) ? part[t - off] : 0;
    __syncthreads();
    part[t] = v + u;
    __syncthreads();
  }
  int run = (t == 0) ? 0 : part[t - 1];
  for (int k = 0; k < CHK; ++k) {
    int i = base + k;
    if (i < N_NODES) { offsets[i] = run; run += counts[i]; }
  }
  if (t == 1023) offsets[N_NODES] = run;
}

// ---- K1: fused GEMMs + bucket/nstart (extra blocks) ----
__global__ __launch_bounds__(256) void fused_gemm(
    const float* __restrict__ h, const float* __restrict__ e,
    const unsigned short* __restrict__ wbf,
    const float* __restrict__ Ab, const float* __restrict__ Bb,
    const float* __restrict__ Db, const float* __restrict__ Eb,
    const float* __restrict__ Cb,
    float* __restrict__ Ah, unsigned short* __restrict__ DB,
    unsigned short* __restrict__ Eh, unsigned short* __restrict__ Ce,
    const int* __restrict__ src, const int* __restrict__ dst,
    const int* __restrict__ counts, const int* __restrict__ offsets,
    int* __restrict__ cursor, int4* __restrict__ meta, int* __restrict__ nstart) {
  __shared__ __align__(16) char lds_x[64 * 256];
  __shared__ __align__(16) char lds_w[128 * 256];
  int lane = threadIdx.x & 63, w = threadIdx.x >> 6;
  int prow = w * 16 + (lane & 15);

  if (blockIdx.x >= NODE_BLOCKS + CE_BLOCKS) {
    // ---- bucket + nstart blocks ----
    int i = (blockIdx.x - NODE_BLOCKS - CE_BLOCKS) * 256 + threadIdx.x;
    if (i < N_EDGES) {
      int d = dst[i];
      int pl = atomicAdd(&cursor[d], 1);
      int p = offsets[d] + pl;
      meta[p] = make_int4(i, src[i], d, (pl == counts[d] - 1) ? 1 : 0);
    }
    if (i <= 8192) {
      if (i == 8192) {
        nstart[i] = N_NODES;
      } else {
        int target = (int)(((long long)i * N_EDGES) >> 13);
        int lo = 0, hi = N_NODES;
        while (lo < hi) {
          int mid = (lo + hi) >> 1;
          if (offsets[mid] < target) lo = mid + 1; else hi = mid;
        }
        nstart[i] = lo;
      }
    }
    return;
  }

  if (blockIdx.x < NODE_BLOCKS) {
    int tile = blockIdx.x * 64;
    int nvalid = N_NODES - tile; if (nvalid > 64) nvalid = 64;
    stage_tile_f32(h, tile, nvalid, lds_x);
    __syncthreads();
    bf16x8 a[4];
#pragma unroll
    for (int ks = 0; ks < 4; ++ks) a[ks] = read_frag(lds_x, prow, ks, lane);

    const int wmat[4] = {0, 1, 3, 4};           // A,B,D,E
    const float* const biases[4] = {Ab, Bb, Db, Eb};
#pragma unroll
    for (int m = 0; m < 4; ++m) {
      __syncthreads();
      stage_w(wbf + wmat[m] * 16384, lds_w);
      __syncthreads();
      f32x4 acc[8] = {};
#pragma unroll
      for (int ct = 0; ct < 8; ++ct) {
#pragma unroll
        for (int ks = 0; ks < 4; ++ks) {
          bf16x8 b = read_frag(lds_w, ct * 16 + (lane & 15), ks, lane);
          acc[ct] = __builtin_amdgcn_mfma_f32_16x16x32_bf16(a[ks], b, acc[ct], 0, 0, 0);
        }
      }
      const float* bias = biases[m];
#pragma unroll
      for (int ct = 0; ct < 8; ++ct) {
        int col = ct * 16 + (lane & 15);
        float bv = bias[col];
#pragma unroll
        for (int j = 0; j < 4; ++j) {
          int r = tile + w * 16 + (lane >> 4) * 4 + j;
          if (r < N_NODES) {
            float v = acc[ct][j] + bv;
            if (m == 0) Ah[(size_t)r * DIM + col] = v;
            else if (m == 1) DB[(size_t)r * 256 + 4 * (col >> 1) + 2 + (col & 1)] = f2bf(v);
            else if (m == 2) DB[(size_t)r * 256 + 4 * (col >> 1) + (col & 1)] = f2bf(v);
            else Eh[(size_t)r * DIM + col] = f2bf(v);
          }
        }
      }
    }
  } else {
    stage_w(wbf + 2 * 16384, lds_w);
    int t0 = blockIdx.x - NODE_BLOCKS;
    int srow = threadIdx.x >> 4, sf = threadIdx.x & 15;
    f32x4 r0[4], r1[4];
    auto gload = [&](int tile) {
#pragma unroll
      for (int it = 0; it < 4; ++it) {
        const f32x4* p = (const f32x4*)(e + (size_t)(tile * 64 + it * 16 + srow) * DIM + sf * 8);
        r0[it] = p[0]; r1[it] = p[1];
      }
    };
    auto lstore = [&]() {
#pragma unroll
      for (int it = 0; it < 4; ++it)
        stage_pack_store(lds_x, it * 16 + srow, sf, r0[it], r1[it]);
    };
    gload(t0);
#pragma unroll 1
    for (int i = 0; i < 5; ++i) {
      int tile = t0 + i * CE_BLOCKS;
      __syncthreads();
      lstore();
      if (i < 4) gload(t0 + (i + 1) * CE_BLOCKS);
      __syncthreads();
      bf16x8 a[4];
#pragma unroll
      for (int ks = 0; ks < 4; ++ks) a[ks] = read_frag(lds_x, prow, ks, lane);
      f32x4 acc[8] = {};
#pragma unroll
      for (int ct = 0; ct < 8; ++ct) {
#pragma unroll
        for (int ks = 0; ks < 4; ++ks) {
          bf16x8 b = read_frag(lds_w, ct * 16 + (lane & 15), ks, lane);
          acc[ct] = __builtin_amdgcn_mfma_f32_16x16x32_bf16(a[ks], b, acc[ct], 0, 0, 0);
        }
      }
#pragma unroll
      for (int ct = 0; ct < 8; ++ct) {
        int col = ct * 16 + (lane & 15);
        float bv = Cb[col];
#pragma unroll
        for (int j = 0; j < 4; ++j) {
          int r = tile * 64 + w * 16 + (lane >> 4) * 4 + j;
          Ce[(size_t)r * DIM + col] = f2bf(acc[ct][j] + bv);
        }
      }
    }
  }
}

// ---- K3: gather over dst-sorted edges, node-aligned wave ranges, depth-5 pipe ----
__global__ __launch_bounds__(256, 8) void edge_gather(
    const int4* __restrict__ meta, const int* __restrict__ offsets,
    const int* __restrict__ nstart,
    const unsigned short* __restrict__ DB, const unsigned short* __restrict__ Eh,
    const unsigned short* __restrict__ Ce, unsigned short* __restrict__ enew,
    const float* __restrict__ Ah, float* __restrict__ hout,
    float* __restrict__ stats) {
  __shared__ float s_stat[512];
  s_stat[threadIdx.x] = 0.f; s_stat[threadIdx.x + 256] = 0.f;
  __syncthreads();
  int lane = threadIdx.x & 63;
  int w = __builtin_amdgcn_readfirstlane(threadIdx.x >> 6);
  int wid = blockIdx.x * 4 + w;
  int ns = nstart[wid], ne = nstart[wid + 1];
  int base = offsets[ns], end = offsets[ne];
  int n = end - base;
  const int4* mp = meta + base;

  float sum0 = 0.f, sum1 = 0.f, q0 = 0.f, q1 = 0.f;      // BN-e
  float hs0 = 0.f, hs1 = 0.f, hq0 = 0.f, hq1 = 0.f;      // BN-h
  float am0 = 0.f, am1 = 0.f, as0 = 0.f, as1 = 0.f;
  int cur_d = -1;
  float eh0 = 0.f, eh1 = 0.f;

  auto issue = [&](const int4& m, unsigned& ce, u32x2& db) {
    ce = *(const unsigned*)(Ce + (size_t)m.x * DIM + 2 * lane);
    db = *(const u32x2*)(DB + (size_t)m.y * 256 + 4 * lane);
  };
  auto flush = [&](int v) {
    float p0 = am0 / (as0 + 1e-6f);
    float p1 = am1 / (as1 + 1e-6f);
    f32x2 a = *(const f32x2*)(Ah + (size_t)v * DIM + 2 * lane);
    p0 += a[0]; p1 += a[1];
    f32x2 o; o[0] = p0; o[1] = p1;
    *(f32x2*)(hout + (size_t)v * DIM + 2 * lane) = o;
    hs0 += p0; hq0 = fmaf(p0, p0, hq0);
    hs1 += p1; hq1 = fmaf(p1, p1, hq1);
    am0 = am1 = as0 = as1 = 0.f;
  };
  auto proc = [&](const int4& m, unsigned ce, u32x2 db) {
    if (m.z != cur_d) {                          // wave-uniform: new dst run
      unsigned p = *(const unsigned*)(Eh + (size_t)m.z * DIM + 2 * lane);
      eh0 = bf2f_lo(p); eh1 = bf2f_hi(p);
      cur_d = m.z;
    }
    float e0 = bf2f_lo(ce) + bf2f_lo(db[0]) + eh0;
    float e1 = bf2f_hi(ce) + bf2f_hi(db[0]) + eh1;
    *(unsigned*)(enew + (size_t)m.x * DIM + 2 * lane) =
        (unsigned)f2bf(e0) | ((unsigned)f2bf(e1) << 16);
    sum0 += e0; q0 = fmaf(e0, e0, q0);
    sum1 += e1; q1 = fmaf(e1, e1, q1);
    float sg0 = 1.f / (1.f + __expf(-e0));
    float sg1 = 1.f / (1.f + __expf(-e1));
    am0 = fmaf(bf2f_lo(db[1]), sg0, am0);
    am1 = fmaf(bf2f_hi(db[1]), sg1, am1);
    as0 += sg0; as1 += sg1;
    if (m.w) flush(m.z);
  };

  const int DEP = 5;
  if (n >= 2 * DEP) {
    int nmain = n - (n % (2 * DEP));
    int4 mA[DEP], mB[DEP];
    unsigned ceA[DEP], ceB[DEP]; u32x2 dbA[DEP], dbB[DEP];
#pragma unroll
    for (int k = 0; k < DEP; ++k) mA[k] = mp[k];
#pragma unroll
    for (int k = 0; k < DEP; ++k) issue(mA[k], ceA[k], dbA[k]);
    for (int j = 0; j < nmain; j += 2 * DEP) {
#pragma unroll
      for (int k = 0; k < DEP; ++k) mB[k] = mp[j + DEP + k];
#pragma unroll
      for (int k = 0; k < DEP; ++k) issue(mB[k], ceB[k], dbB[k]);
#pragma unroll
      for (int k = 0; k < DEP; ++k) proc(mA[k], ceA[k], dbA[k]);
      if (j + 2 * DEP < nmain) {
#pragma unroll
        for (int k = 0; k < DEP; ++k) mA[k] = mp[j + 2 * DEP + k];
#pragma unroll
        for (int k = 0; k < DEP; ++k) issue(mA[k], ceA[k], dbA[k]);
      }
#pragma unroll
      for (int k = 0; k < DEP; ++k) proc(mB[k], ceB[k], dbB[k]);
    }
    for (int j = nmain; j < n; ++j) {
      int4 m = mp[j];
      unsigned ce; u32x2 db;
      issue(m, ce, db);
      proc(m, ce, db);
    }
  } else if (n > 0) {
    for (int j = 0; j < n; ++j) {
      int4 m = mp[j];
      unsigned ce; u32x2 db;
      issue(m, ce, db);
      proc(m, ce, db);
    }
  }

  // degree-0 nodes: pre = Ah
  for (int v0 = ns; v0 < ne; v0 += 64) {
    int v = v0 + lane;
    bool z = false;
    if (v < ne) z = (offsets[v] == offsets[v + 1]);
    unsigned long long mask = __ballot(z);
    while (mask) {
      int bit = __builtin_ctzll(mask); mask &= mask - 1;
      int vz = v0 + bit;
      f32x2 a = *(const f32x2*)(Ah + (size_t)vz * DIM + 2 * lane);
      *(f32x2*)(hout + (size_t)vz * DIM + 2 * lane) = a;
      hs0 += a[0]; hq0 = fmaf(a[0], a[0], hq0);
      hs1 += a[1]; hq1 = fmaf(a[1], a[1], hq1);
    }
  }

  atomicAdd(&s_stat[2 * lane], sum0);        atomicAdd(&s_stat[2 * lane + 1], sum1);
  atomicAdd(&s_stat[128 + 2 * lane], q0);    atomicAdd(&s_stat[128 + 2 * lane + 1], q1);
  atomicAdd(&s_stat[256 + 2 * lane], hs0);   atomicAdd(&s_stat[256 + 2 * lane + 1], hs1);
  atomicAdd(&s_stat[384 + 2 * lane], hq0);   atomicAdd(&s_stat[384 + 2 * lane + 1], hq1);
  __syncthreads();
  atomicAdd(stats + threadIdx.x, s_stat[threadIdx.x]);
  atomicAdd(stats + threadIdx.x + 256, s_stat[threadIdx.x + 256]);
}

// ---- finalize both BN scale/shift ----
__global__ void finalize_both(const float* __restrict__ stats,
                              const float* __restrict__ bn_e_g, const float* __restrict__ bn_e_b,
                              const float* __restrict__ bn_h_g, const float* __restrict__ bn_h_b,
                              float* __restrict__ scale_e, float* __restrict__ shift_e,
                              float* __restrict__ scale_h, float* __restrict__ shift_h) {
  int t = threadIdx.x;
  if (t < 128) {
    float mu = stats[t] / (float)N_EDGES;
    float var = stats[128 + t] / (float)N_EDGES - mu * mu;
    float inv = rsqrtf(var + 1e-5f);
    float sc = bn_e_g[t] * inv;
    scale_e[t] = sc;
    shift_e[t] = bn_e_b[t] - mu * sc;
  } else {
    int c = t - 128;
    float mu = stats[256 + c] / (float)N_NODES;
    float var = stats[384 + c] / (float)N_NODES - mu * mu;
    float inv = rsqrtf(var + 1e-5f);
    float sc = bn_h_g[c] * inv;
    scale_h[c] = sc;
    shift_h[c] = bn_h_b[c] - mu * sc;
  }
}

// ---- apply_all: 8192 resident waves; 2-deep pipelined e-stream ----
__global__ __launch_bounds__(256) void apply_all(
    const float* __restrict__ e, const unsigned short* __restrict__ enew,
    const float* __restrict__ scale_e, const float* __restrict__ shift_e,
    float* __restrict__ eout,
    const float* __restrict__ h, float* __restrict__ hout,
    const float* __restrict__ scale_h, const float* __restrict__ shift_h) {
  const size_t stride = (size_t)APPLY_BLOCKS * 256;
  const size_t idx0 = (size_t)blockIdx.x * 256 + threadIdx.x;

  // h part (~3 iters)
  {
    const size_t total_h4 = (size_t)N_NODES * DIM / 4;
    f32x4 sc4 = ((const f32x4*)scale_h)[idx0 & 31];
    f32x4 sh4 = ((const f32x4*)shift_h)[idx0 & 31];
    for (size_t i = idx0; i < total_h4; i += stride) {
      f32x4 p = ((const f32x4*)hout)[i];
      f32x4 hv = ((const f32x4*)h)[i];
      f32x4 o;
#pragma unroll
      for (int j = 0; j < 4; ++j) o[j] = hv[j] + fmaxf(p[j] * sc4[j] + sh4[j], 0.f);
      ((f32x4*)hout)[i] = o;
    }
  }
  // e part (~37 iters), 2-deep guarded prefetch
  {
    const size_t total_e4 = (size_t)N_EDGES * DIM / 4;
    int colbase = (int)((idx0 * 4) & (DIM - 1));        // constant per thread
    f32x4 sc4 = *(const f32x4*)(scale_e + colbase);
    f32x4 sh4 = *(const f32x4*)(shift_e + colbase);
    u32x2 enA = {0, 0}, enB = {0, 0};
    f32x4 evA = {0, 0, 0, 0}, evB = {0, 0, 0, 0};
    if (idx0 < total_e4) { enA = ((const u32x2*)enew)[idx0]; evA = ((const f32x4*)e)[idx0]; }
    if (idx0 + stride < total_e4) {
      enB = ((const u32x2*)enew)[idx0 + stride];
      evB = ((const f32x4*)e)[idx0 + stride];
    }
    for (size_t i = idx0; i < total_e4; i += stride) {
      size_t n2 = i + 2 * stride;
      u32x2 enN = {0, 0}; f32x4 evN = {0, 0, 0, 0};
      if (n2 < total_e4) { enN = ((const u32x2*)enew)[n2]; evN = ((const f32x4*)e)[n2]; }
      f32x4 o;
      o[0] = evA[0] + fmaxf(bf2f_lo(enA[0]) * sc4[0] + sh4[0], 0.f);
      o[1] = evA[1] + fmaxf(bf2f_hi(enA[0]) * sc4[1] + sh4[1], 0.f);
      o[2] = evA[2] + fmaxf(bf2f_lo(enA[1]) * sc4[2] + sh4[2], 0.f);
      o[3] = evA[3] + fmaxf(bf2f_hi(enA[1]) * sc4[3] + sh4[3], 0.f);
      ((f32x4*)eout)[i] = o;
      enA = enB; evA = evB; enB = enN; evB = evN;
    }
  }
}

extern "C" void kernel_launch(void* const* d_in, const int* in_sizes, int n_in,
                              void* d_out, int out_size, void* d_ws, size_t ws_size,
                              hipStream_t stream) {
  const float* h   = (const float*)d_in[0];
  const float* e   = (const float*)d_in[1];
  const int*   src = (const int*)d_in[2];
  const int*   dst = (const int*)d_in[3];
  const float* Aw = (const float*)d_in[4];  const float* Ab = (const float*)d_in[5];
  const float* Bw = (const float*)d_in[6];  const float* Bb = (const float*)d_in[7];
  const float* Cw = (const float*)d_in[8];  const float* Cb = (const float*)d_in[9];
  const float* Dw = (const float*)d_in[10]; const float* Db = (const float*)d_in[11];
  const float* Ew = (const float*)d_in[12]; const float* Eb = (const float*)d_in[13];
  const float* bn_h_g = (const float*)d_in[14]; const float* bn_h_b = (const float*)d_in[15];
  const float* bn_e_g = (const float*)d_in[16]; const float* bn_e_b = (const float*)d_in[17];

  const size_t ND_F32 = (size_t)N_NODES * DIM * 4;   // 25.6 MB
  const size_t ND_BF  = (size_t)N_NODES * DIM * 2;   // 12.8 MB
  const size_t ED_BF  = (size_t)N_EDGES * DIM * 2;   // 153.6 MB
  char* ws = (char*)d_ws;
  unsigned short* wbf = (unsigned short*)ws;          // 163840 B
  size_t off = 163840;
  float* Ah = (float*)(ws + off);                   off += ND_F32;
  unsigned short* DB = (unsigned short*)(ws + off); off += 2 * ND_BF;
  unsigned short* Eh = (unsigned short*)(ws + off); off += ND_BF;
  unsigned short* Ce = (unsigned short*)(ws + off);   off += ED_BF;
  unsigned short* enew = (unsigned short*)(ws + off); off += ED_BF;
  // ---- zeroed region: counts, cursor, stats (~404 KB) ----
  char* zero_base = ws + off;
  int* counts  = (int*)(ws + off);   off += 200000;
  int* cursor  = (int*)(ws + off);   off += 200000;
  float* stats = (float*)(ws + off); off += 4096;
  size_t zero_bytes = (size_t)(ws + off - zero_base);
  // ---- not zeroed (fully rewritten each call) ----
  int* offsets = (int*)(ws + off);   off += 200064;   // 50001 ints padded
  int* nstart  = (int*)(ws + off);   off += 32832;    // 8193 ints padded
  int4* meta   = (int4*)(ws + off);  off += (size_t)N_EDGES * 16;

  float* scale_e = stats + 512, *shift_e = stats + 640;
  float* scale_h = stats + 768, *shift_h = stats + 896;

  float* hout = (float*)d_out;
  float* eout = (float*)d_out + (size_t)N_NODES * DIM;

  hipMemsetAsync(zero_base, 0, zero_bytes, stream);

  setup_kernel<<<(N_EDGES + 255) / 256, 256, 0, stream>>>(Aw, Bw, Cw, Dw, Ew, wbf,
      dst, counts);
  scan_kernel<<<1, 1024, 0, stream>>>(counts, offsets);
  fused_gemm<<<NODE_BLOCKS + CE_BLOCKS + BUCKET_BLOCKS, 256, 0, stream>>>(
      h, e, wbf, Ab, Bb, Db, Eb, Cb, Ah, DB, Eh, Ce,
      src, dst, counts, offsets, cursor, meta, nstart);
  edge_gather<<<GATHER_BLOCKS, 256, 0, stream>>>(meta, offsets, nstart, DB, Eh, Ce, enew,
      Ah, hout, stats);
  finalize_both<<<1, 256, 0, stream>>>(stats, bn_e_g, bn_e_b, bn_h_g, bn_h_b,
      scale_e, shift_e, scale_h, shift_h);
  apply_all<<<APPLY_BLOCKS, 256, 0, stream>>>(e, enew, scale_e, shift_e, eout,
      h, hout, scale_h, shift_h);
}

// Round 11
// 597.459 us; speedup vs baseline: 1.0926x; 1.0926x over previous
//
#include <hip/hip_runtime.h>
#include <stdint.h>

#define N_NODES 50000
#define N_EDGES 600000
#define DIM 128
#define N_TILES (N_EDGES / 64)   // 9375
#define NODE_BLOCKS 782          // ceil(50000/64)
#define CE_BLOCKS 1875           // 9375 / 5 tiles each, exact
#define GATHER_BLOCKS 2048       // 8192 waves, node-aligned ranges
#define APPLY_BLOCKS 2048        // 8192 waves, exactly resident

typedef __attribute__((ext_vector_type(8))) short bf16x8;
typedef __attribute__((ext_vector_type(4))) float f32x4;
typedef __attribute__((ext_vector_type(2))) float f32x2;
typedef __attribute__((ext_vector_type(4))) unsigned int u32x4;
typedef __attribute__((ext_vector_type(2))) unsigned int u32x2;

__device__ inline unsigned short f2bf(float f) {
  unsigned u = __builtin_bit_cast(unsigned, f);
  unsigned r = 0x7fffu + ((u >> 16) & 1u);
  return (unsigned short)((u + r) >> 16);
}
__device__ inline float bf2f_lo(unsigned p) { return __builtin_bit_cast(float, p << 16); }
__device__ inline float bf2f_hi(unsigned p) { return __builtin_bit_cast(float, p & 0xffff0000u); }

// ---- LDS staging (swizzled bf16 tiles, row stride 256 B) ----
__device__ inline void stage_pack_store(char* lds, int row, int f, f32x4 v0, f32x4 v1) {
  u32x4 q;
  q[0] = (unsigned)f2bf(v0[0]) | ((unsigned)f2bf(v0[1]) << 16);
  q[1] = (unsigned)f2bf(v0[2]) | ((unsigned)f2bf(v0[3]) << 16);
  q[2] = (unsigned)f2bf(v1[0]) | ((unsigned)f2bf(v1[1]) << 16);
  q[3] = (unsigned)f2bf(v1[2]) | ((unsigned)f2bf(v1[3]) << 16);
  int byte = (f * 16) ^ ((row & 7) << 4);
  *(u32x4*)(lds + row * 256 + byte) = q;
}

__device__ inline void stage_tile_f32(const float* __restrict__ src, int row0,
                                      int nvalid, char* lds) {
#pragma unroll
  for (int it = 0; it < 4; ++it) {
    int c = it * 256 + threadIdx.x;
    int row = c >> 4, f = c & 15;
    f32x4 v0 = {0, 0, 0, 0}, v1 = {0, 0, 0, 0};
    if (row < nvalid) {
      const f32x4* p = (const f32x4*)(src + (size_t)(row0 + row) * DIM + f * 8);
      v0 = p[0]; v1 = p[1];
    }
    stage_pack_store(lds, row, f, v0, v1);
  }
}

__device__ inline void stage_w(const unsigned short* __restrict__ wbf, char* lds) {
#pragma unroll
  for (int it = 0; it < 8; ++it) {
    int c = it * 256 + threadIdx.x;
    int row = c >> 4, f = c & 15;
    u32x4 q = *(const u32x4*)(wbf + row * 128 + f * 8);
    int byte = (f * 16) ^ ((row & 7) << 4);
    *(u32x4*)(lds + row * 256 + byte) = q;
  }
}

__device__ inline bf16x8 read_frag(const char* lds, int row, int ks, int lane) {
  int byte = ks * 64 + ((lane >> 4) * 16);
  byte ^= ((row & 7) << 4);
  return *(const bf16x8*)(lds + row * 256 + byte);
}

// ---- K0: weight conversion + dst histogram ----
__global__ void setup_kernel(const float* __restrict__ a, const float* __restrict__ b,
                             const float* __restrict__ c, const float* __restrict__ d,
                             const float* __restrict__ e5, unsigned short* __restrict__ out,
                             const int* __restrict__ dst, int* __restrict__ counts) {
  int i = blockIdx.x * 256 + threadIdx.x;
  if (i < 5 * 16384) {
    int m = i >> 14, k = i & 16383;
    const float* p = (m == 0) ? a : (m == 1) ? b : (m == 2) ? c : (m == 3) ? d : e5;
    out[i] = f2bf(p[k]);
  }
  if (i < N_EDGES) atomicAdd(&counts[dst[i]], 1);
}

__global__ __launch_bounds__(1024) void scan_kernel(const int* __restrict__ counts,
                                                    int* __restrict__ offsets) {
  __shared__ int part[1024];
  const int CHK = 49;
  int t = threadIdx.x;
  int base = t * CHK;
  int s = 0;
  for (int k = 0; k < CHK; ++k) {
    int i = base + k;
    if (i < N_NODES) s += counts[i];
  }
  part[t] = s;
  __syncthreads();
  for (int off = 1; off < 1024; off <<= 1) {
    int v = part[t];
    int u = (t >= off) ? part[t - off] : 0;
    __syncthreads();
    part[t] = v + u;
    __syncthreads();
  }
  int run = (t == 0) ? 0 : part[t - 1];
  for (int k = 0; k < CHK; ++k) {
    int i = base + k;
    if (i < N_NODES) { offsets[i] = run; run += counts[i]; }
  }
  if (t == 1023) offsets[N_NODES] = run;
}

// meta[p] = (edge, src, dst, last-of-run flag); node-aligned wave ranges
__global__ void bucket_kernel(const int* __restrict__ src, const int* __restrict__ dst,
                              const int* __restrict__ counts,
                              const int* __restrict__ offsets, int* __restrict__ cursor,
                              int4* __restrict__ meta, int* __restrict__ nstart) {
  int i = blockIdx.x * 256 + threadIdx.x;
  if (i < N_EDGES) {
    int d = dst[i];
    int pl = atomicAdd(&cursor[d], 1);
    int p = offsets[d] + pl;
    meta[p] = make_int4(i, src[i], d, (pl == counts[d] - 1) ? 1 : 0);
  }
  if (i <= 8192) {
    if (i == 8192) {
      nstart[i] = N_NODES;
    } else {
      int target = (int)(((long long)i * N_EDGES) >> 13);
      int lo = 0, hi = N_NODES;
      while (lo < hi) {
        int mid = (lo + hi) >> 1;
        if (offsets[mid] < target) lo = mid + 1; else hi = mid;
      }
      nstart[i] = lo;
    }
  }
}

// ---- K1: fused GEMMs ----
__global__ __launch_bounds__(256) void fused_gemm(
    const float* __restrict__ h, const float* __restrict__ e,
    const unsigned short* __restrict__ wbf,
    const float* __restrict__ Ab, const float* __restrict__ Bb,
    const float* __restrict__ Db, const float* __restrict__ Eb,
    const float* __restrict__ Cb,
    float* __restrict__ Ah, unsigned short* __restrict__ DB,
    unsigned short* __restrict__ Eh, unsigned short* __restrict__ Ce) {
  __shared__ __align__(16) char lds_x[64 * 256];
  __shared__ __align__(16) char lds_w[128 * 256];
  int lane = threadIdx.x & 63, w = threadIdx.x >> 6;
  int prow = w * 16 + (lane & 15);

  if (blockIdx.x < NODE_BLOCKS) {
    int tile = blockIdx.x * 64;
    int nvalid = N_NODES - tile; if (nvalid > 64) nvalid = 64;
    stage_tile_f32(h, tile, nvalid, lds_x);
    __syncthreads();
    bf16x8 a[4];
#pragma unroll
    for (int ks = 0; ks < 4; ++ks) a[ks] = read_frag(lds_x, prow, ks, lane);

    const int wmat[4] = {0, 1, 3, 4};           // A,B,D,E
    const float* const biases[4] = {Ab, Bb, Db, Eb};
#pragma unroll
    for (int m = 0; m < 4; ++m) {
      __syncthreads();
      stage_w(wbf + wmat[m] * 16384, lds_w);
      __syncthreads();
      f32x4 acc[8] = {};
#pragma unroll
      for (int ct = 0; ct < 8; ++ct) {
#pragma unroll
        for (int ks = 0; ks < 4; ++ks) {
          bf16x8 b = read_frag(lds_w, ct * 16 + (lane & 15), ks, lane);
          acc[ct] = __builtin_amdgcn_mfma_f32_16x16x32_bf16(a[ks], b, acc[ct], 0, 0, 0);
        }
      }
      const float* bias = biases[m];
#pragma unroll
      for (int ct = 0; ct < 8; ++ct) {
        int col = ct * 16 + (lane & 15);
        float bv = bias[col];
#pragma unroll
        for (int j = 0; j < 4; ++j) {
          int r = tile + w * 16 + (lane >> 4) * 4 + j;
          if (r < N_NODES) {
            float v = acc[ct][j] + bv;
            if (m == 0) Ah[(size_t)r * DIM + col] = v;
            else if (m == 1) DB[(size_t)r * 256 + 4 * (col >> 1) + 2 + (col & 1)] = f2bf(v);
            else if (m == 2) DB[(size_t)r * 256 + 4 * (col >> 1) + (col & 1)] = f2bf(v);
            else Eh[(size_t)r * DIM + col] = f2bf(v);
          }
        }
      }
    }
  } else {
    stage_w(wbf + 2 * 16384, lds_w);
    int t0 = blockIdx.x - NODE_BLOCKS;
    int srow = threadIdx.x >> 4, sf = threadIdx.x & 15;
    f32x4 r0[4], r1[4];
    auto gload = [&](int tile) {
#pragma unroll
      for (int it = 0; it < 4; ++it) {
        const f32x4* p = (const f32x4*)(e + (size_t)(tile * 64 + it * 16 + srow) * DIM + sf * 8);
        r0[it] = p[0]; r1[it] = p[1];
      }
    };
    auto lstore = [&]() {
#pragma unroll
      for (int it = 0; it < 4; ++it)
        stage_pack_store(lds_x, it * 16 + srow, sf, r0[it], r1[it]);
    };
    gload(t0);
#pragma unroll 1
    for (int i = 0; i < 5; ++i) {
      int tile = t0 + i * CE_BLOCKS;
      __syncthreads();
      lstore();
      if (i < 4) gload(t0 + (i + 1) * CE_BLOCKS);
      __syncthreads();
      bf16x8 a[4];
#pragma unroll
      for (int ks = 0; ks < 4; ++ks) a[ks] = read_frag(lds_x, prow, ks, lane);
      f32x4 acc[8] = {};
#pragma unroll
      for (int ct = 0; ct < 8; ++ct) {
#pragma unroll
        for (int ks = 0; ks < 4; ++ks) {
          bf16x8 b = read_frag(lds_w, ct * 16 + (lane & 15), ks, lane);
          acc[ct] = __builtin_amdgcn_mfma_f32_16x16x32_bf16(a[ks], b, acc[ct], 0, 0, 0);
        }
      }
#pragma unroll
      for (int ct = 0; ct < 8; ++ct) {
        int col = ct * 16 + (lane & 15);
        float bv = Cb[col];
#pragma unroll
        for (int j = 0; j < 4; ++j) {
          int r = tile * 64 + w * 16 + (lane >> 4) * 4 + j;
          Ce[(size_t)r * DIM + col] = f2bf(acc[ct][j] + bv);
        }
      }
    }
  }
}

// ---- K3: gather over dst-sorted edges, node-aligned wave ranges, depth-4 pipe.
// Eh cached per dst-run in registers (wave-uniform run switch). ----
__global__ __launch_bounds__(256, 8) void edge_gather(
    const int4* __restrict__ meta, const int* __restrict__ offsets,
    const int* __restrict__ nstart,
    const unsigned short* __restrict__ DB, const unsigned short* __restrict__ Eh,
    const unsigned short* __restrict__ Ce, unsigned short* __restrict__ enew,
    const float* __restrict__ Ah, float* __restrict__ hout,
    float* __restrict__ stats) {
  __shared__ float s_stat[512];
  s_stat[threadIdx.x] = 0.f; s_stat[threadIdx.x + 256] = 0.f;
  __syncthreads();
  int lane = threadIdx.x & 63;
  int w = __builtin_amdgcn_readfirstlane(threadIdx.x >> 6);
  int wid = blockIdx.x * 4 + w;
  int ns = nstart[wid], ne = nstart[wid + 1];
  int base = offsets[ns], end = offsets[ne];
  int n = end - base;
  const int4* mp = meta + base;

  float sum0 = 0.f, sum1 = 0.f, q0 = 0.f, q1 = 0.f;      // BN-e
  float hs0 = 0.f, hs1 = 0.f, hq0 = 0.f, hq1 = 0.f;      // BN-h
  float am0 = 0.f, am1 = 0.f, as0 = 0.f, as1 = 0.f;
  int cur_d = -1;
  float eh0 = 0.f, eh1 = 0.f;

  auto issue = [&](const int4& m, unsigned& ce, u32x2& db) {
    ce = *(const unsigned*)(Ce + (size_t)m.x * DIM + 2 * lane);
    db = *(const u32x2*)(DB + (size_t)m.y * 256 + 4 * lane);
  };
  auto flush = [&](int v) {
    float p0 = am0 / (as0 + 1e-6f);
    float p1 = am1 / (as1 + 1e-6f);
    f32x2 a = *(const f32x2*)(Ah + (size_t)v * DIM + 2 * lane);
    p0 += a[0]; p1 += a[1];
    f32x2 o; o[0] = p0; o[1] = p1;
    *(f32x2*)(hout + (size_t)v * DIM + 2 * lane) = o;
    hs0 += p0; hq0 = fmaf(p0, p0, hq0);
    hs1 += p1; hq1 = fmaf(p1, p1, hq1);
    am0 = am1 = as0 = as1 = 0.f;
  };
  auto proc = [&](const int4& m, unsigned ce, u32x2 db) {
    if (m.z != cur_d) {                          // wave-uniform: new dst run
      unsigned p = *(const unsigned*)(Eh + (size_t)m.z * DIM + 2 * lane);
      eh0 = bf2f_lo(p); eh1 = bf2f_hi(p);
      cur_d = m.z;
    }
    float e0 = bf2f_lo(ce) + bf2f_lo(db[0]) + eh0;
    float e1 = bf2f_hi(ce) + bf2f_hi(db[0]) + eh1;
    *(unsigned*)(enew + (size_t)m.x * DIM + 2 * lane) =
        (unsigned)f2bf(e0) | ((unsigned)f2bf(e1) << 16);
    sum0 += e0; q0 = fmaf(e0, e0, q0);
    sum1 += e1; q1 = fmaf(e1, e1, q1);
    float sg0 = 1.f / (1.f + __expf(-e0));
    float sg1 = 1.f / (1.f + __expf(-e1));
    am0 = fmaf(bf2f_lo(db[1]), sg0, am0);
    am1 = fmaf(bf2f_hi(db[1]), sg1, am1);
    as0 += sg0; as1 += sg1;
    if (m.w) flush(m.z);
  };

  if (n >= 8) {
    int nmain = n & ~7;
    int4 mA[4], mB[4];
    unsigned ceA[4], ceB[4]; u32x2 dbA[4], dbB[4];
#pragma unroll
    for (int k = 0; k < 4; ++k) mA[k] = mp[k];
#pragma unroll
    for (int k = 0; k < 4; ++k) issue(mA[k], ceA[k], dbA[k]);
    for (int j = 0; j < nmain; j += 8) {
#pragma unroll
      for (int k = 0; k < 4; ++k) mB[k] = mp[j + 4 + k];
#pragma unroll
      for (int k = 0; k < 4; ++k) issue(mB[k], ceB[k], dbB[k]);
#pragma unroll
      for (int k = 0; k < 4; ++k) proc(mA[k], ceA[k], dbA[k]);
      if (j + 8 < nmain) {
#pragma unroll
        for (int k = 0; k < 4; ++k) mA[k] = mp[j + 8 + k];
#pragma unroll
        for (int k = 0; k < 4; ++k) issue(mA[k], ceA[k], dbA[k]);
      }
#pragma unroll
      for (int k = 0; k < 4; ++k) proc(mB[k], ceB[k], dbB[k]);
    }
    for (int j = nmain; j < n; ++j) {
      int4 m = mp[j];
      unsigned ce; u32x2 db;
      issue(m, ce, db);
      proc(m, ce, db);
    }
  } else if (n > 0) {
    for (int j = 0; j < n; ++j) {
      int4 m = mp[j];
      unsigned ce; u32x2 db;
      issue(m, ce, db);
      proc(m, ce, db);
    }
  }

  // degree-0 nodes: pre = Ah
  for (int v0 = ns; v0 < ne; v0 += 64) {
    int v = v0 + lane;
    bool z = false;
    if (v < ne) z = (offsets[v] == offsets[v + 1]);
    unsigned long long mask = __ballot(z);
    while (mask) {
      int bit = __builtin_ctzll(mask); mask &= mask - 1;
      int vz = v0 + bit;
      f32x2 a = *(const f32x2*)(Ah + (size_t)vz * DIM + 2 * lane);
      *(f32x2*)(hout + (size_t)vz * DIM + 2 * lane) = a;
      hs0 += a[0]; hq0 = fmaf(a[0], a[0], hq0);
      hs1 += a[1]; hq1 = fmaf(a[1], a[1], hq1);
    }
  }

  atomicAdd(&s_stat[2 * lane], sum0);        atomicAdd(&s_stat[2 * lane + 1], sum1);
  atomicAdd(&s_stat[128 + 2 * lane], q0);    atomicAdd(&s_stat[128 + 2 * lane + 1], q1);
  atomicAdd(&s_stat[256 + 2 * lane], hs0);   atomicAdd(&s_stat[256 + 2 * lane + 1], hs1);
  atomicAdd(&s_stat[384 + 2 * lane], hq0);   atomicAdd(&s_stat[384 + 2 * lane + 1], hq1);
  __syncthreads();
  atomicAdd(stats + threadIdx.x, s_stat[threadIdx.x]);
  atomicAdd(stats + threadIdx.x + 256, s_stat[threadIdx.x + 256]);
}

// ---- finalize both BN scale/shift ----
__global__ void finalize_both(const float* __restrict__ stats,
                              const float* __restrict__ bn_e_g, const float* __restrict__ bn_e_b,
                              const float* __restrict__ bn_h_g, const float* __restrict__ bn_h_b,
                              float* __restrict__ scale_e, float* __restrict__ shift_e,
                              float* __restrict__ scale_h, float* __restrict__ shift_h) {
  int t = threadIdx.x;
  if (t < 128) {
    float mu = stats[t] / (float)N_EDGES;
    float var = stats[128 + t] / (float)N_EDGES - mu * mu;
    float inv = rsqrtf(var + 1e-5f);
    float sc = bn_e_g[t] * inv;
    scale_e[t] = sc;
    shift_e[t] = bn_e_b[t] - mu * sc;
  } else {
    int c = t - 128;
    float mu = stats[256 + c] / (float)N_NODES;
    float var = stats[384 + c] / (float)N_NODES - mu * mu;
    float inv = rsqrtf(var + 1e-5f);
    float sc = bn_h_g[c] * inv;
    scale_h[c] = sc;
    shift_h[c] = bn_h_b[c] - mu * sc;
  }
}

// ---- apply_all: 8192 resident waves, software-pipelined streaming ----
__global__ __launch_bounds__(256) void apply_all(
    const float* __restrict__ e, const unsigned short* __restrict__ enew,
    const float* __restrict__ scale_e, const float* __restrict__ shift_e,
    float* __restrict__ eout,
    const float* __restrict__ h, float* __restrict__ hout,
    const float* __restrict__ scale_h, const float* __restrict__ shift_h) {
  const size_t stride = (size_t)APPLY_BLOCKS * 256;
  const size_t idx0 = (size_t)blockIdx.x * 256 + threadIdx.x;

  // h part: ~3 iterations; colbase constant (stride % 32 == 0 in f32x4 units)
  {
    const size_t total_h4 = (size_t)N_NODES * DIM / 4;
    f32x4 sc4 = ((const f32x4*)scale_h)[idx0 & 31];
    f32x4 sh4 = ((const f32x4*)shift_h)[idx0 & 31];
    for (size_t i = idx0; i < total_h4; i += stride) {
      f32x4 p = ((const f32x4*)hout)[i];
      f32x4 hv = ((const f32x4*)h)[i];
      f32x4 o;
#pragma unroll
      for (int j = 0; j < 4; ++j) o[j] = hv[j] + fmaxf(p[j] * sc4[j] + sh4[j], 0.f);
      ((f32x4*)hout)[i] = o;
    }
  }
  // e part: ~37 iterations, pipelined (next loads issued before current store)
  {
    const size_t total_e4 = (size_t)N_EDGES * DIM / 4;
    int colbase = (int)((idx0 * 4) & (DIM - 1));        // constant per thread
    f32x4 sc4 = *(const f32x4*)(scale_e + colbase);
    f32x4 sh4 = *(const f32x4*)(shift_e + colbase);
    u32x2 en_c = {0, 0}; f32x4 ev_c = {0, 0, 0, 0};
    if (idx0 < total_e4) {
      en_c = ((const u32x2*)enew)[idx0];
      ev_c = ((const f32x4*)e)[idx0];
    }
    for (size_t i = idx0; i < total_e4; i += stride) {
      size_t nx = i + stride;
      u32x2 en_n = {0, 0}; f32x4 ev_n = {0, 0, 0, 0};
      if (nx < total_e4) {
        en_n = ((const u32x2*)enew)[nx];
        ev_n = ((const f32x4*)e)[nx];
      }
      f32x4 o;
      o[0] = ev_c[0] + fmaxf(bf2f_lo(en_c[0]) * sc4[0] + sh4[0], 0.f);
      o[1] = ev_c[1] + fmaxf(bf2f_hi(en_c[0]) * sc4[1] + sh4[1], 0.f);
      o[2] = ev_c[2] + fmaxf(bf2f_lo(en_c[1]) * sc4[2] + sh4[2], 0.f);
      o[3] = ev_c[3] + fmaxf(bf2f_hi(en_c[1]) * sc4[3] + sh4[3], 0.f);
      ((f32x4*)eout)[i] = o;
      en_c = en_n; ev_c = ev_n;
    }
  }
}

extern "C" void kernel_launch(void* const* d_in, const int* in_sizes, int n_in,
                              void* d_out, int out_size, void* d_ws, size_t ws_size,
                              hipStream_t stream) {
  const float* h   = (const float*)d_in[0];
  const float* e   = (const float*)d_in[1];
  const int*   src = (const int*)d_in[2];
  const int*   dst = (const int*)d_in[3];
  const float* Aw = (const float*)d_in[4];  const float* Ab = (const float*)d_in[5];
  const float* Bw = (const float*)d_in[6];  const float* Bb = (const float*)d_in[7];
  const float* Cw = (const float*)d_in[8];  const float* Cb = (const float*)d_in[9];
  const float* Dw = (const float*)d_in[10]; const float* Db = (const float*)d_in[11];
  const float* Ew = (const float*)d_in[12]; const float* Eb = (const float*)d_in[13];
  const float* bn_h_g = (const float*)d_in[14]; const float* bn_h_b = (const float*)d_in[15];
  const float* bn_e_g = (const float*)d_in[16]; const float* bn_e_b = (const float*)d_in[17];

  const size_t ND_F32 = (size_t)N_NODES * DIM * 4;   // 25.6 MB
  const size_t ND_BF  = (size_t)N_NODES * DIM * 2;   // 12.8 MB
  const size_t ED_BF  = (size_t)N_EDGES * DIM * 2;   // 153.6 MB
  char* ws = (char*)d_ws;
  unsigned short* wbf = (unsigned short*)ws;          // 163840 B
  size_t off = 163840;
  float* Ah = (float*)(ws + off);                   off += ND_F32;
  unsigned short* DB = (unsigned short*)(ws + off); off += 2 * ND_BF;
  unsigned short* Eh = (unsigned short*)(ws + off); off += ND_BF;
  unsigned short* Ce = (unsigned short*)(ws + off);   off += ED_BF;
  unsigned short* enew = (unsigned short*)(ws + off); off += ED_BF;
  // ---- zeroed region: counts, cursor, stats (~404 KB) ----
  char* zero_base = ws + off;
  int* counts  = (int*)(ws + off);   off += 200000;
  int* cursor  = (int*)(ws + off);   off += 200000;
  float* stats = (float*)(ws + off); off += 4096;
  size_t zero_bytes = (size_t)(ws + off - zero_base);
  // ---- not zeroed (fully rewritten each call) ----
  int* offsets = (int*)(ws + off);   off += 200064;   // 50001 ints padded
  int* nstart  = (int*)(ws + off);   off += 32832;    // 8193 ints padded
  int4* meta   = (int4*)(ws + off);  off += (size_t)N_EDGES * 16;

  float* scale_e = stats + 512, *shift_e = stats + 640;
  float* scale_h = stats + 768, *shift_h = stats + 896;

  float* hout = (float*)d_out;
  float* eout = (float*)d_out + (size_t)N_NODES * DIM;

  hipMemsetAsync(zero_base, 0, zero_bytes, stream);

  setup_kernel<<<(N_EDGES + 255) / 256, 256, 0, stream>>>(Aw, Bw, Cw, Dw, Ew, wbf,
      dst, counts);
  scan_kernel<<<1, 1024, 0, stream>>>(counts, offsets);
  bucket_kernel<<<(N_EDGES + 255) / 256, 256, 0, stream>>>(src, dst, counts, offsets,
      cursor, meta, nstart);
  fused_gemm<<<NODE_BLOCKS + CE_BLOCKS, 256, 0, stream>>>(h, e, wbf, Ab, Bb, Db, Eb, Cb,
      Ah, DB, Eh, Ce);
  edge_gather<<<GATHER_BLOCKS, 256, 0, stream>>>(meta, offsets, nstart, DB, Eh, Ce, enew,
      Ah, hout, stats);
  finalize_both<<<1, 256, 0, stream>>>(stats, bn_e_g, bn_e_b, bn_h_g, bn_h_b,
      scale_e, shift_e, scale_h, shift_h);
  apply_all<<<APPLY_BLOCKS, 256, 0, stream>>>(e, enew, scale_e, shift_e, eout,
      h, hout, scale_h, shift_h);
}